// Round 3
// baseline (5158.330 us; speedup 1.0000x reference)
//
#include <hip/hip_runtime.h>
#include <float.h>

#define N_PTS   50000
#define M_CENT  2048
#define K_LOC   32
#define C_CH    128

typedef unsigned long long u64;
typedef unsigned int u32;

// ---------------- FPS ----------------
// 14 blocks x 512 threads (112 waves, 7 pts/lane). Per iteration:
//   per-wave 6-step butterfly (v_max_f64 on packed keys) -> LDS (dbl-buffered)
//   -> barrier -> wave0 3-step reduce -> ONE agent store per block (own line)
//   -> all waves poll 14 slots (pipelined double-probe, 16-lane replication)
//   -> 4-step butterfly + candidate-pos prefetch + coord broadcast.
// Slot ring R=64 with owner zeroing of slot (i-2) after poll of i completes
// (all stored i => all finished poll of i-1 => all finished poll of i-2, so
// nobody still reads slot i-2; zero->fresh same-thread same-address ordering
// is coherence-guaranteed; 62-iteration (~70us) propagation slack).
#define FPS_NB   14
#define FPS_NT   512
#define FPS_PPT  7      // 112 waves * 64 * 7 = 50176 >= 50000; wave 111 first pt 49728 < N
#define FPS_R    64     // ring depth (power of 2)
#define SLOT_U64 8      // 64B stride: one cache line per block slot

__global__ void init_ws_kernel(u64* __restrict__ slots) {
  int t = blockIdx.x * blockDim.x + threadIdx.x;
  if (t < FPS_R * FPS_NB * SLOT_U64) slots[t] = 0ull;
}

__global__ __launch_bounds__(FPS_NT) void fps_kernel(
    const float* __restrict__ pos,
    u64* __restrict__ slots,       // [FPS_R * FPS_NB * SLOT_U64], zeroed
    float* __restrict__ cent_out)  // d_out[0 .. 3*M_CENT)
{
  const int lane = threadIdx.x & 63;
  const int wv   = threadIdx.x >> 6;          // 0..7
  const int blk  = blockIdx.x;                // 0..13
  const int w    = blk * (FPS_NT/64) + wv;    // global wave 0..111

  float px[FPS_PPT], py[FPS_PPT], pz[FPS_PPT], dist[FPS_PPT];
#pragma unroll
  for (int j = 0; j < FPS_PPT; j++) {
    int n = (w * FPS_PPT + j) * 64 + lane;
    if (n < N_PTS) {
      px[j] = pos[3*n+0]; py[j] = pos[3*n+1]; pz[j] = pos[3*n+2];
      dist[j] = FLT_MAX;               // matches finfo(f32).max init
    } else {
      px[j] = 0.f; py[j] = 0.f; pz[j] = 0.f; dist[j] = -1.f;  // never contributes
    }
  }

  __shared__ double redD[2][FPS_NT/64];   // double-buffered per-wave bests

  // iteration 0 centroid = point 0 (deterministic start, matches reference)
  float cx = pos[0], cy = pos[1], cz = pos[2];

  for (int i = 0; i < M_CENT; i++) {
    if (blk == 0 && wv == 0 && lane == 0) {
      cent_out[3*i+0] = cx; cent_out[3*i+1] = cy; cent_out[3*i+2] = cz;
    }
    // packed key as positive f64 bit pattern: high32 = dist bits (>=0, not
    // huge => exponent field never 0x7FF => never NaN/Inf), low32 = ~idx.
    // u64 ordering == f64 ordering for positive patterns => v_max_f64 works.
    double best = 0.0;
#pragma unroll
    for (int j = 0; j < FPS_PPT; j++) {
      int n = (w * FPS_PPT + j) * 64 + lane;
      if (n < N_PTS) {
        // exact reference arithmetic: no FMA contraction, ((dx^2+dy^2)+dz^2)
        float dx = __fsub_rn(px[j], cx);
        float dy = __fsub_rn(py[j], cy);
        float dz = __fsub_rn(pz[j], cz);
        float d2 = __fadd_rn(__fadd_rn(__fmul_rn(dx,dx), __fmul_rn(dy,dy)),
                             __fmul_rn(dz,dz));
        float d  = fminf(dist[j], d2);
        dist[j] = d;
        u64 pk = ((u64)__float_as_uint(d) << 32) | (u64)(0xFFFFFFFFu - (u32)n);
        best = fmax(best, __longlong_as_double((long long)pk));
      }
    }
    // in-wave butterfly (6 steps, v_max_f64)
#pragma unroll
    for (int off = 32; off; off >>= 1)
      best = fmax(best, __shfl_xor(best, off, 64));

    if (i == M_CENT - 1) break;   // last winner never consumed

    if (lane == 0) redD[i & 1][wv] = best;
    __syncthreads();
    if (wv == 0) {
      double b2 = (lane < FPS_NT/64) ? redD[i & 1][lane] : 0.0;
#pragma unroll
      for (int off = 4; off; off >>= 1)
        b2 = fmax(b2, __shfl_xor(b2, off, 64));
      if (lane == 0)
        __hip_atomic_store(&slots[(size_t)(i & (FPS_R-1)) * (FPS_NB*SLOT_U64)
                                  + blk * SLOT_U64],
                           (u64)__double_as_longlong(b2),
                           __ATOMIC_RELAXED, __HIP_MEMORY_SCOPE_AGENT);
    }

    // poll: 16-lane replicated (cslot = lane&15); sentinel for cslot >= NB
    const int cslot = lane & 15;
    u64 got = (cslot < FPS_NB) ? 0ull : 1ull;
    const u64* sl = slots + (size_t)(i & (FPS_R-1)) * (FPS_NB*SLOT_U64)
                          + cslot * SLOT_U64;
    while (__ballot(got == 0ull)) {
      u64 a = 0, b = 0;
      if (got == 0ull) {   // pipelined double-probe: check a while b in flight
        a = __hip_atomic_load(sl, __ATOMIC_RELAXED, __HIP_MEMORY_SCOPE_AGENT);
        b = __hip_atomic_load(sl, __ATOMIC_RELAXED, __HIP_MEMORY_SCOPE_AGENT);
      }
      got = got ? got : (a ? a : b);
    }

    // retire slot (i-2): safe per header comment, off critical path
    if (wv == 0 && lane == 0 && i >= 2)
      __hip_atomic_store(&slots[(size_t)((i-2) & (FPS_R-1)) * (FPS_NB*SLOT_U64)
                                + blk * SLOT_U64],
                         0ull, __ATOMIC_RELAXED, __HIP_MEMORY_SCOPE_AGENT);

    // candidate-pos prefetch (hidden behind winner butterfly)
    u64 pkv = (cslot < FPS_NB) ? got : 0ull;
    u32 ic  = 0xFFFFFFFFu - (u32)pkv;
    float qx = 0.f, qy = 0.f, qz = 0.f;
    if (cslot < FPS_NB) { qx = pos[3*ic]; qy = pos[3*ic+1]; qz = pos[3*ic+2]; }

    double wb = __longlong_as_double((long long)pkv);
#pragma unroll
    for (int off = 8; off; off >>= 1)
      wb = fmax(wb, __shfl_xor(wb, off, 64));
    u64 win = (u64)__double_as_longlong(wb);

    u64 msk = __ballot(pkv == win && cslot < FPS_NB);  // >=1 lane; key unique
    int L = __ffsll((long long)msk) - 1;
    cx = __shfl(qx, L, 64); cy = __shfl(qy, L, 64); cz = __shfl(qz, L, 64);
  }
}

// ---------------- Ball query ----------------
#define BQ_NT  256
#define BQ_CAP 2048   // expected ~209 candidates/centroid; huge safety margin

__global__ __launch_bounds__(BQ_NT) void ballq_kernel(
    const float* __restrict__ pos,
    const float* __restrict__ cent,   // centroid coords (from d_out)
    int* __restrict__ nbr,            // [M_CENT*K_LOC]
    int* __restrict__ nsel)           // [M_CENT]
{
  __shared__ float s_d2[BQ_CAP];
  __shared__ int   s_idx[BQ_CAP];
  __shared__ int   s_count;
  __shared__ u64   s_red[BQ_NT/64];
  __shared__ u64   s_win;

  const int m = blockIdx.x, tid = threadIdx.x;
  if (tid == 0) s_count = 0;
  __syncthreads();
  const float cx = cent[3*m+0], cy = cent[3*m+1], cz = cent[3*m+2];

  for (int n = tid; n < N_PTS; n += BQ_NT) {
    float dx = __fsub_rn(cx, pos[3*n+0]);
    float dy = __fsub_rn(cy, pos[3*n+1]);
    float dz = __fsub_rn(cz, pos[3*n+2]);
    float d2 = __fadd_rn(__fadd_rn(__fmul_rn(dx,dx), __fmul_rn(dy,dy)),
                         __fmul_rn(dz,dz));
    if (d2 <= 0.01f) {   // same f32 value as (float)(0.1*0.1)
      int p = atomicAdd(&s_count, 1);
      if (p < BQ_CAP) { s_d2[p] = d2; s_idx[p] = n; }
    }
  }
  __syncthreads();
  int cnt = s_count; if (cnt > BQ_CAP) cnt = BQ_CAP;
  int ns = cnt < K_LOC ? cnt : K_LOC;

  // exact top_k semantics: k smallest d2, ties -> smaller index
  for (int sel = 0; sel < ns; sel++) {
    u64 best = ~0ull;
    for (int p = tid; p < cnt; p += BQ_NT) {
      u64 pk = ((u64)__float_as_uint(s_d2[p]) << 32) | (u64)(u32)s_idx[p];
      if (pk < best) best = pk;
    }
#pragma unroll
    for (int off = 32; off >= 1; off >>= 1) {
      u64 o = __shfl_down(best, off, 64);
      if (o < best) best = o;
    }
    if ((tid & 63) == 0) s_red[tid >> 6] = best;
    __syncthreads();
    if (tid < 64) {
      best = (tid < BQ_NT/64) ? s_red[tid] : ~0ull;
#pragma unroll
      for (int off = 2; off >= 1; off >>= 1) {
        u64 o = __shfl_down(best, off, 64);
        if (o < best) best = o;
      }
      if (tid == 0) s_win = best;
    }
    __syncthreads();
    int widx = (int)(u32)(s_win & 0xFFFFFFFFull);
    if (tid == 0) nbr[m*K_LOC + sel] = widx;
    for (int p = tid; p < cnt; p += BQ_NT) {
      if (s_idx[p] == widx) s_d2[p] = FLT_MAX;   // remove winner
    }
    __syncthreads();
  }
  if (tid == 0) nsel[m] = ns;
}

// ---------------- Gather + max-pool + channel mix ----------------
// Max over the valid selected set == reference (fallback idx is the nearest
// valid neighbor, already a member of the set).
__global__ __launch_bounds__(C_CH) void pool_mix_kernel(
    const float* __restrict__ fs,   // (N,128,1)
    const float* __restrict__ fv,   // (N,128,3)
    const float* __restrict__ Ws,
    const float* __restrict__ Wv,
    const float* __restrict__ bs,
    const float* __restrict__ bv,
    const int* __restrict__ nbr,
    const int* __restrict__ nsel,
    float* __restrict__ out_s,      // (M,128,1)
    float* __restrict__ out_v)      // (M,128,3)
{
  __shared__ float ps[C_CH];
  __shared__ float pv[C_CH*3];
  const int m = blockIdx.x, o = threadIdx.x;
  const int ns = nsel[m];
  float mS = -FLT_MAX, m0 = -FLT_MAX, m1 = -FLT_MAX, m2 = -FLT_MAX;
  for (int j = 0; j < ns; j++) {
    int n = nbr[m*K_LOC + j];
    mS = fmaxf(mS, fs[(size_t)n*C_CH + o]);
    const float* r = fv + (size_t)n*(C_CH*3) + 3*o;
    m0 = fmaxf(m0, r[0]); m1 = fmaxf(m1, r[1]); m2 = fmaxf(m2, r[2]);
  }
  ps[o] = mS; pv[3*o+0] = m0; pv[3*o+1] = m1; pv[3*o+2] = m2;
  __syncthreads();
  float aS = bs[o];
  float a0 = bv[o], a1 = bv[o], a2 = bv[o];
  for (int cc = 0; cc < C_CH; cc++) {
    float w1 = Ws[cc*C_CH + o];
    float w2 = Wv[cc*C_CH + o];
    aS = fmaf(ps[cc], w1, aS);
    a0 = fmaf(pv[3*cc+0], w2, a0);
    a1 = fmaf(pv[3*cc+1], w2, a1);
    a2 = fmaf(pv[3*cc+2], w2, a2);
  }
  out_s[(size_t)m*C_CH + o] = aS;
  float* ov = out_v + (size_t)m*(C_CH*3) + 3*o;
  ov[0] = a0; ov[1] = a1; ov[2] = a2;
}

extern "C" void kernel_launch(void* const* d_in, const int* in_sizes, int n_in,
                              void* d_out, int out_size, void* d_ws, size_t ws_size,
                              hipStream_t stream) {
  (void)in_sizes; (void)n_in; (void)out_size; (void)ws_size;
  const float* pos = (const float*)d_in[0];
  const float* fs  = (const float*)d_in[1];
  const float* fv  = (const float*)d_in[2];
  const float* Ws  = (const float*)d_in[3];
  const float* Wv  = (const float*)d_in[4];
  const float* bs  = (const float*)d_in[5];
  const float* bv  = (const float*)d_in[6];

  float* out      = (float*)d_out;
  float* cent_out = out;                               // 2048*3
  float* out_s    = out + 3*M_CENT;                    // 2048*128
  float* out_v    = out + 3*M_CENT + M_CENT*C_CH;      // 2048*128*3

  char* ws = (char*)d_ws;
  u64* slots = (u64*)ws;                               // 64*14*8*8B = 57344 B
  size_t slots_bytes = (size_t)FPS_R * FPS_NB * SLOT_U64 * 8;
  int* nbr   = (int*)(ws + slots_bytes);               // 256 KB
  int* nsel  = (int*)(ws + slots_bytes + (size_t)M_CENT*K_LOC*4);

  init_ws_kernel<<<(FPS_R*FPS_NB*SLOT_U64 + 255)/256, 256, 0, stream>>>(slots);
  fps_kernel<<<FPS_NB, FPS_NT, 0, stream>>>(pos, slots, cent_out);
  ballq_kernel<<<M_CENT, BQ_NT, 0, stream>>>(pos, cent_out, nbr, nsel);
  pool_mix_kernel<<<M_CENT, C_CH, 0, stream>>>(fs, fv, Ws, Wv, bs, bv,
                                               nbr, nsel, out_s, out_v);
}

// Round 4
// 4315.854 us; speedup vs baseline: 1.1952x; 1.1952x over previous
//
#include <hip/hip_runtime.h>
#include <float.h>

#define N_PTS   50000
#define M_CENT  2048
#define K_LOC   32
#define C_CH    128

typedef unsigned long long u64;
typedef unsigned int u32;

// ---------------- FPS ----------------
// 14 blocks x 512 threads (112 waves, 7 pts/lane). Per iteration:
//   all 8 waves: update + 6-step butterfly (v_max_f64 on packed keys) -> LDS
//   -> barrier -> WAVE 0 ONLY: 3-step reduce over 8 wave-bests, one agent
//   store to this block's own 64B line, then lanes 0..13 poll the 14 slots
//   (the ONLY fabric pollers in the block: 14 waves x 14 lanes = 196 probes
//   in flight chip-wide, 14 per line -- R2 had 3136, R3 ~900/line, both
//   congested the coherence point), 4-step winner butterfly with overlapped
//   candidate-coord prefetch, publish winner coords to LDS -> barrier.
// Sibling waves wait at s_barrier: zero fabric traffic while leader polls.
//
// Slot ring R=64, owner-zeroed: leader zeroes its own slot in row (i-2)
// right after storing row i. Safe: I stored row i => I completed poll of
// row i-1 => all blocks stored row i-1 => (program order) all blocks
// finished reading row i-2. Zero->reuse visibility slack = 62 iterations
// (~60us). Rows 0..63 pre-zeroed by init kernel; row r is re-zeroed at
// iteration r+2, 62 iterations before its reuse at r+64.
#define FPS_NB   14
#define FPS_NT   512
#define FPS_PPT  7      // 112 waves * 64 * 7 = 50176 >= 50000
#define FPS_R    64     // ring depth (power of 2)
#define SLOT_U64 8      // 64B stride: one cache line per block slot

__global__ void init_ws_kernel(u64* __restrict__ slots) {
  int t = blockIdx.x * blockDim.x + threadIdx.x;
  if (t < FPS_R * FPS_NB * SLOT_U64) slots[t] = 0ull;
}

__global__ __launch_bounds__(FPS_NT) void fps_kernel(
    const float* __restrict__ pos,
    u64* __restrict__ slots,       // [FPS_R * FPS_NB * SLOT_U64], zeroed
    float* __restrict__ cent_out)  // d_out[0 .. 3*M_CENT)
{
  const int lane = threadIdx.x & 63;
  const int wv   = threadIdx.x >> 6;          // 0..7
  const int blk  = blockIdx.x;                // 0..13
  const int w    = blk * (FPS_NT/64) + wv;    // global wave 0..111

  float px[FPS_PPT], py[FPS_PPT], pz[FPS_PPT], dist[FPS_PPT];
#pragma unroll
  for (int j = 0; j < FPS_PPT; j++) {
    int n = (w * FPS_PPT + j) * 64 + lane;
    if (n < N_PTS) {
      px[j] = pos[3*n+0]; py[j] = pos[3*n+1]; pz[j] = pos[3*n+2];
      dist[j] = FLT_MAX;               // matches finfo(f32).max init
    } else {
      px[j] = 0.f; py[j] = 0.f; pz[j] = 0.f; dist[j] = -1.f;  // never contributes
    }
  }

  __shared__ double s_wbest[2][FPS_NT/64];  // per-wave bests (dbl-buffered)
  __shared__ float  s_bc[2][3];             // winner coords broadcast

  // iteration 0 centroid = point 0 (deterministic start, matches reference)
  float cx = pos[0], cy = pos[1], cz = pos[2];

  for (int i = 0; i < M_CENT; i++) {
    if (blk == 0 && wv == 0 && lane == 0) {
      cent_out[3*i+0] = cx; cent_out[3*i+1] = cy; cent_out[3*i+2] = cz;
    }
    // packed key as positive f64 bit pattern: high32 = dist bits (>=0,
    // exponent never 0x7FF), low32 = ~idx. u64 order == f64 order for
    // positive patterns => v_max_f64 is a 1-instr 64-bit ordered max.
    double best = 0.0;
#pragma unroll
    for (int j = 0; j < FPS_PPT; j++) {
      int n = (w * FPS_PPT + j) * 64 + lane;
      if (n < N_PTS) {
        // exact reference arithmetic: no FMA contraction, ((dx^2+dy^2)+dz^2)
        float dx = __fsub_rn(px[j], cx);
        float dy = __fsub_rn(py[j], cy);
        float dz = __fsub_rn(pz[j], cz);
        float d2 = __fadd_rn(__fadd_rn(__fmul_rn(dx,dx), __fmul_rn(dy,dy)),
                             __fmul_rn(dz,dz));
        float d  = fminf(dist[j], d2);
        dist[j] = d;
        u64 pk = ((u64)__float_as_uint(d) << 32) | (u64)(0xFFFFFFFFu - (u32)n);
        best = fmax(best, __longlong_as_double((long long)pk));
      }
    }
#pragma unroll
    for (int off = 32; off; off >>= 1)
      best = fmax(best, __shfl_xor(best, off, 64));

    if (i == M_CENT - 1) break;   // last winner never consumed

    if (lane == 0) s_wbest[i & 1][wv] = best;
    __syncthreads();

    if (wv == 0) {
      // ---- leader wave: block reduce + store + poll + winner broadcast ----
      double b2 = (lane < FPS_NT/64) ? s_wbest[i & 1][lane] : 0.0;
#pragma unroll
      for (int off = 4; off; off >>= 1)
        b2 = fmax(b2, __shfl_xor(b2, off, 64));
      u64* row = slots + (size_t)(i & (FPS_R-1)) * (FPS_NB*SLOT_U64);
      if (lane == 0) {
        __hip_atomic_store(&row[blk * SLOT_U64], (u64)__double_as_longlong(b2),
                           __ATOMIC_RELAXED, __HIP_MEMORY_SCOPE_AGENT);
        if (i >= 2)   // retire own slot in row (i-2); safe per header proof
          __hip_atomic_store(&slots[(size_t)((i-2) & (FPS_R-1)) * (FPS_NB*SLOT_U64)
                                    + blk * SLOT_U64],
                             0ull, __ATOMIC_RELAXED, __HIP_MEMORY_SCOPE_AGENT);
      }
      // poll: lane l (l < 14) waits on slot l; single probe per trip
      u64 got = (lane < FPS_NB) ? 0ull : 1ull;
      const u64* sl = row + lane * SLOT_U64;
      while (__ballot(got == 0ull)) {
        if (got == 0ull)
          got = __hip_atomic_load(sl, __ATOMIC_RELAXED, __HIP_MEMORY_SCOPE_AGENT);
      }
      // candidate-coord prefetch, overlapped with the winner butterfly
      u64 pkv = (lane < FPS_NB) ? got : 0ull;
      u32 ic  = 0xFFFFFFFFu - (u32)pkv;
      float qx = 0.f, qy = 0.f, qz = 0.f;
      if (lane < FPS_NB) { qx = pos[3*ic]; qy = pos[3*ic+1]; qz = pos[3*ic+2]; }

      double wb = __longlong_as_double((long long)pkv);
#pragma unroll
      for (int off = 8; off; off >>= 1)
        wb = fmax(wb, __shfl_xor(wb, off, 64));
      u64 win = (u64)__double_as_longlong(wb);

      u64 msk = __ballot(pkv == win && lane < FPS_NB);  // keys globally unique
      int L = __ffsll((long long)msk) - 1;
      float ncx = __shfl(qx, L, 64);
      float ncy = __shfl(qy, L, 64);
      float ncz = __shfl(qz, L, 64);
      if (lane == 0) {
        s_bc[i & 1][0] = ncx; s_bc[i & 1][1] = ncy; s_bc[i & 1][2] = ncz;
      }
    }
    __syncthreads();
    cx = s_bc[i & 1][0]; cy = s_bc[i & 1][1]; cz = s_bc[i & 1][2];
  }
}

// ---------------- Ball query ----------------
#define BQ_NT  256
#define BQ_CAP 2048   // expected ~209 candidates/centroid; huge safety margin

__global__ __launch_bounds__(BQ_NT) void ballq_kernel(
    const float* __restrict__ pos,
    const float* __restrict__ cent,   // centroid coords (from d_out)
    int* __restrict__ nbr,            // [M_CENT*K_LOC]
    int* __restrict__ nsel)           // [M_CENT]
{
  __shared__ float s_d2[BQ_CAP];
  __shared__ int   s_idx[BQ_CAP];
  __shared__ int   s_count;
  __shared__ u64   s_red[BQ_NT/64];
  __shared__ u64   s_win;

  const int m = blockIdx.x, tid = threadIdx.x;
  if (tid == 0) s_count = 0;
  __syncthreads();
  const float cx = cent[3*m+0], cy = cent[3*m+1], cz = cent[3*m+2];

  for (int n = tid; n < N_PTS; n += BQ_NT) {
    float dx = __fsub_rn(cx, pos[3*n+0]);
    float dy = __fsub_rn(cy, pos[3*n+1]);
    float dz = __fsub_rn(cz, pos[3*n+2]);
    float d2 = __fadd_rn(__fadd_rn(__fmul_rn(dx,dx), __fmul_rn(dy,dy)),
                         __fmul_rn(dz,dz));
    if (d2 <= 0.01f) {   // same f32 value as (float)(0.1*0.1)
      int p = atomicAdd(&s_count, 1);
      if (p < BQ_CAP) { s_d2[p] = d2; s_idx[p] = n; }
    }
  }
  __syncthreads();
  int cnt = s_count; if (cnt > BQ_CAP) cnt = BQ_CAP;
  int ns = cnt < K_LOC ? cnt : K_LOC;

  // exact top_k semantics: k smallest d2, ties -> smaller index
  for (int sel = 0; sel < ns; sel++) {
    u64 best = ~0ull;
    for (int p = tid; p < cnt; p += BQ_NT) {
      u64 pk = ((u64)__float_as_uint(s_d2[p]) << 32) | (u64)(u32)s_idx[p];
      if (pk < best) best = pk;
    }
#pragma unroll
    for (int off = 32; off >= 1; off >>= 1) {
      u64 o = __shfl_down(best, off, 64);
      if (o < best) best = o;
    }
    if ((tid & 63) == 0) s_red[tid >> 6] = best;
    __syncthreads();
    if (tid < 64) {
      best = (tid < BQ_NT/64) ? s_red[tid] : ~0ull;
#pragma unroll
      for (int off = 2; off >= 1; off >>= 1) {
        u64 o = __shfl_down(best, off, 64);
        if (o < best) best = o;
      }
      if (tid == 0) s_win = best;
    }
    __syncthreads();
    int widx = (int)(u32)(s_win & 0xFFFFFFFFull);
    if (tid == 0) nbr[m*K_LOC + sel] = widx;
    for (int p = tid; p < cnt; p += BQ_NT) {
      if (s_idx[p] == widx) s_d2[p] = FLT_MAX;   // remove winner
    }
    __syncthreads();
  }
  if (tid == 0) nsel[m] = ns;
}

// ---------------- Gather + max-pool + channel mix ----------------
// Max over the valid selected set == reference (fallback idx is the nearest
// valid neighbor, already a member of the set).
__global__ __launch_bounds__(C_CH) void pool_mix_kernel(
    const float* __restrict__ fs,   // (N,128,1)
    const float* __restrict__ fv,   // (N,128,3)
    const float* __restrict__ Ws,
    const float* __restrict__ Wv,
    const float* __restrict__ bs,
    const float* __restrict__ bv,
    const int* __restrict__ nbr,
    const int* __restrict__ nsel,
    float* __restrict__ out_s,      // (M,128,1)
    float* __restrict__ out_v)      // (M,128,3)
{
  __shared__ float ps[C_CH];
  __shared__ float pv[C_CH*3];
  const int m = blockIdx.x, o = threadIdx.x;
  const int ns = nsel[m];
  float mS = -FLT_MAX, m0 = -FLT_MAX, m1 = -FLT_MAX, m2 = -FLT_MAX;
  for (int j = 0; j < ns; j++) {
    int n = nbr[m*K_LOC + j];
    mS = fmaxf(mS, fs[(size_t)n*C_CH + o]);
    const float* r = fv + (size_t)n*(C_CH*3) + 3*o;
    m0 = fmaxf(m0, r[0]); m1 = fmaxf(m1, r[1]); m2 = fmaxf(m2, r[2]);
  }
  ps[o] = mS; pv[3*o+0] = m0; pv[3*o+1] = m1; pv[3*o+2] = m2;
  __syncthreads();
  float aS = bs[o];
  float a0 = bv[o], a1 = bv[o], a2 = bv[o];
  for (int cc = 0; cc < C_CH; cc++) {
    float w1 = Ws[cc*C_CH + o];
    float w2 = Wv[cc*C_CH + o];
    aS = fmaf(ps[cc], w1, aS);
    a0 = fmaf(pv[3*cc+0], w2, a0);
    a1 = fmaf(pv[3*cc+1], w2, a1);
    a2 = fmaf(pv[3*cc+2], w2, a2);
  }
  out_s[(size_t)m*C_CH + o] = aS;
  float* ov = out_v + (size_t)m*(C_CH*3) + 3*o;
  ov[0] = a0; ov[1] = a1; ov[2] = a2;
}

extern "C" void kernel_launch(void* const* d_in, const int* in_sizes, int n_in,
                              void* d_out, int out_size, void* d_ws, size_t ws_size,
                              hipStream_t stream) {
  (void)in_sizes; (void)n_in; (void)out_size; (void)ws_size;
  const float* pos = (const float*)d_in[0];
  const float* fs  = (const float*)d_in[1];
  const float* fv  = (const float*)d_in[2];
  const float* Ws  = (const float*)d_in[3];
  const float* Wv  = (const float*)d_in[4];
  const float* bs  = (const float*)d_in[5];
  const float* bv  = (const float*)d_in[6];

  float* out      = (float*)d_out;
  float* cent_out = out;                               // 2048*3
  float* out_s    = out + 3*M_CENT;                    // 2048*128
  float* out_v    = out + 3*M_CENT + M_CENT*C_CH;      // 2048*128*3

  char* ws = (char*)d_ws;
  u64* slots = (u64*)ws;                               // 64*14*8*8B = 57344 B
  size_t slots_bytes = (size_t)FPS_R * FPS_NB * SLOT_U64 * 8;
  int* nbr   = (int*)(ws + slots_bytes);               // 256 KB
  int* nsel  = (int*)(ws + slots_bytes + (size_t)M_CENT*K_LOC*4);

  init_ws_kernel<<<(FPS_R*FPS_NB*SLOT_U64 + 255)/256, 256, 0, stream>>>(slots);
  fps_kernel<<<FPS_NB, FPS_NT, 0, stream>>>(pos, slots, cent_out);
  ballq_kernel<<<M_CENT, BQ_NT, 0, stream>>>(pos, cent_out, nbr, nsel);
  pool_mix_kernel<<<M_CENT, C_CH, 0, stream>>>(fs, fv, Ws, Wv, bs, bv,
                                               nbr, nsel, out_s, out_v);
}

// Round 7
// 4094.180 us; speedup vs baseline: 1.2599x; 1.0541x over previous
//
#include <hip/hip_runtime.h>
#include <float.h>

#define N_PTS   50000
#define M_CENT  2048
#define K_LOC   32
#define C_CH    128

typedef unsigned long long u64;
typedef unsigned int u32;

// ---------------- FPS ----------------
// R4-proven protocol (14 blocks x 512, agent-scope slots, leader-wave-only
// polling) with all cross-lane reductions moved from ds_bpermute shuffle
// butterflies (~40-120 cyc/dependent step on the LDS pipe) to DPP chains
// (~8 cyc/step on the VALU): row_shr 1/2/4/8 + row_bcast 15/31 + readlane.
// u64 (dist,idx) reductions are split into two 32-bit phases -- max dist,
// then min index among dist-ties -- bit-identical winner to the u64 max
// (reference argmax = first max index).
//
// Slot ring R=64, owner-zeroed at (i-2): I stored row i => I completed poll
// of row i-1 => all blocks stored row i-1 => all finished reading row i-2.
// 62-iteration reuse slack; rows pre-zeroed by init kernel.
#define FPS_NB   14
#define FPS_NT   512
#define FPS_PPT  7      // 112 waves * 64 * 7 = 50176 >= 50000
#define FPS_R    64     // ring depth (power of 2)
#define SLOT_U64 8      // 64B stride: one cache line per block slot

__global__ void init_ws_kernel(u64* __restrict__ slots) {
  int t = blockIdx.x * blockDim.x + threadIdx.x;
  if (t < FPS_R * FPS_NB * SLOT_U64) slots[t] = 0ull;
}

// ---- DPP wave-wide reductions (ctrl must be a literal constant) ----
template <int CTRL>
__device__ __forceinline__ u32 dppmov_u(u32 v) {
  return (u32)__builtin_amdgcn_update_dpp((int)v, (int)v, CTRL, 0xf, 0xf, false);
}
template <int CTRL>
__device__ __forceinline__ float dppmov_f(float v) {
  return __int_as_float(
      __builtin_amdgcn_update_dpp(__float_as_int(v), __float_as_int(v),
                                  CTRL, 0xf, 0xf, false));
}
__device__ __forceinline__ float wave_max_f32(float v) {
  v = fmaxf(v, dppmov_f<0x111>(v));   // row_shr:1
  v = fmaxf(v, dppmov_f<0x112>(v));   // row_shr:2
  v = fmaxf(v, dppmov_f<0x114>(v));   // row_shr:4
  v = fmaxf(v, dppmov_f<0x118>(v));   // row_shr:8
  v = fmaxf(v, dppmov_f<0x142>(v));   // row_bcast:15
  v = fmaxf(v, dppmov_f<0x143>(v));   // row_bcast:31
  return __int_as_float(__builtin_amdgcn_readlane(__float_as_int(v), 63));
}
__device__ __forceinline__ u32 wave_max_u32(u32 v) {
  u32 t;
  t = dppmov_u<0x111>(v); v = v > t ? v : t;
  t = dppmov_u<0x112>(v); v = v > t ? v : t;
  t = dppmov_u<0x114>(v); v = v > t ? v : t;
  t = dppmov_u<0x118>(v); v = v > t ? v : t;
  t = dppmov_u<0x142>(v); v = v > t ? v : t;
  t = dppmov_u<0x143>(v); v = v > t ? v : t;
  return (u32)__builtin_amdgcn_readlane((int)v, 63);
}
__device__ __forceinline__ u32 wave_min_u32(u32 v) {
  u32 t;
  t = dppmov_u<0x111>(v); v = v < t ? v : t;
  t = dppmov_u<0x112>(v); v = v < t ? v : t;
  t = dppmov_u<0x114>(v); v = v < t ? v : t;
  t = dppmov_u<0x118>(v); v = v < t ? v : t;
  t = dppmov_u<0x142>(v); v = v < t ? v : t;
  t = dppmov_u<0x143>(v); v = v < t ? v : t;
  return (u32)__builtin_amdgcn_readlane((int)v, 63);
}

__global__ __launch_bounds__(FPS_NT) void fps_kernel(
    const float* __restrict__ pos,
    u64* __restrict__ slots,       // [FPS_R][FPS_NB][SLOT_U64], zeroed
    float* __restrict__ cent_out)  // d_out[0 .. 3*M_CENT)
{
  const int lane = threadIdx.x & 63;
  const int wv   = threadIdx.x >> 6;          // 0..7
  const int blk  = blockIdx.x;                // 0..13
  const int w    = blk * (FPS_NT/64) + wv;    // global wave 0..111

  float px[FPS_PPT], py[FPS_PPT], pz[FPS_PPT], dist[FPS_PPT];
#pragma unroll
  for (int j = 0; j < FPS_PPT; j++) {
    int n = (w * FPS_PPT + j) * 64 + lane;
    if (n < N_PTS) {
      px[j] = pos[3*n+0]; py[j] = pos[3*n+1]; pz[j] = pos[3*n+2];
      dist[j] = FLT_MAX;               // matches finfo(f32).max init
    } else {
      px[j] = 0.f; py[j] = 0.f; pz[j] = 0.f; dist[j] = -1.f;  // never wins
    }
  }

  __shared__ uint2 s_w[2][FPS_NT/64];   // per-wave (dist bits, idx), dbl-buf
  __shared__ float s_bc[2][3];          // winner coords broadcast

  // iteration 0 centroid = point 0 (deterministic start, matches reference)
  float cx = pos[0], cy = pos[1], cz = pos[2];

  for (int i = 0; i < M_CENT; i++) {
    if (blk == 0 && wv == 0 && lane == 0) {
      cent_out[3*i+0] = cx; cent_out[3*i+1] = cy; cent_out[3*i+2] = cz;
    }
    // phase 1: update dists, track lane-local max value only
    float lmax = -1.0f;
#pragma unroll
    for (int j = 0; j < FPS_PPT; j++) {
      int n = (w * FPS_PPT + j) * 64 + lane;
      if (n < N_PTS) {
        // exact reference arithmetic: no FMA contraction, ((dx^2+dy^2)+dz^2)
        float dx = __fsub_rn(px[j], cx);
        float dy = __fsub_rn(py[j], cy);
        float dz = __fsub_rn(pz[j], cz);
        float d2 = __fadd_rn(__fadd_rn(__fmul_rn(dx,dx), __fmul_rn(dy,dy)),
                             __fmul_rn(dz,dz));
        float d  = fminf(dist[j], d2);
        dist[j] = d;
        lmax = fmaxf(lmax, d);
      }
    }
    // phase 2: wave max dist (DPP), then min index among ties (DPP)
    float wmax = wave_max_f32(lmax);   // >= 0 (dists >= 0; lmax=-1 never wins)
    u32 li = 0xFFFFFFFFu;
#pragma unroll
    for (int j = 0; j < FPS_PPT; j++) {
      int n = (w * FPS_PPT + j) * 64 + lane;
      if (n < N_PTS && dist[j] == wmax) li = li < (u32)n ? li : (u32)n;
    }
    u32 widx = wave_min_u32(li);

    if (i == M_CENT - 1) break;   // last winner never consumed

    if (lane == 0) s_w[i & 1][wv] = make_uint2(__float_as_uint(wmax), widx);
    __syncthreads();

    if (wv == 0) {
      // ---- leader wave: block reduce + store + poll + winner select ----
      uint2 kv = (lane < FPS_NT/64) ? s_w[i & 1][lane]
                                    : make_uint2(0u, 0xFFFFFFFFu);
      // dist bits are IEEE >= 0 -> u32 order == float order
      u32 bmaxb = wave_max_u32(kv.x);
      u32 bidx  = wave_min_u32(kv.x == bmaxb ? kv.y : 0xFFFFFFFFu);
      u64* row = slots + (size_t)(i & (FPS_R-1)) * (FPS_NB*SLOT_U64);
      if (lane == 0) {
        u64 key = ((u64)bmaxb << 32) | (u64)(0xFFFFFFFFu - bidx);
        __hip_atomic_store(&row[blk * SLOT_U64], key,
                           __ATOMIC_RELAXED, __HIP_MEMORY_SCOPE_AGENT);
        if (i >= 2)   // retire own slot in row (i-2); safe per header proof
          __hip_atomic_store(&slots[(size_t)((i-2) & (FPS_R-1)) * (FPS_NB*SLOT_U64)
                                    + blk * SLOT_U64],
                             0ull, __ATOMIC_RELAXED, __HIP_MEMORY_SCOPE_AGENT);
      }
      // poll: lane l (l < 14) waits on slot l; single probe per trip
      u64 got = (lane < FPS_NB) ? 0ull : 1ull;
      const u64* sl = row + lane * SLOT_U64;
      while (__ballot(got == 0ull)) {
        if (got == 0ull)
          got = __hip_atomic_load(sl, __ATOMIC_RELAXED, __HIP_MEMORY_SCOPE_AGENT);
      }
      u32 hi = (u32)(got >> 32), lo = (u32)got;
      // candidate-coord prefetch, overlapped with the winner DPP chains
      u32 ic = 0xFFFFFFFFu - lo;
      float qx = 0.f, qy = 0.f, qz = 0.f;
      if (lane < FPS_NB) { qx = pos[3*ic]; qy = pos[3*ic+1]; qz = pos[3*ic+2]; }

      u32 H  = wave_max_u32(lane < FPS_NB ? hi : 0u);
      u32 LO = wave_max_u32((lane < FPS_NB && hi == H) ? lo : 0u); // lo=~idx
      u64 msk = __ballot(lane < FPS_NB && hi == H && lo == LO);    // unique
      int L = __ffsll((long long)msk) - 1;
      float ncx = __int_as_float(__builtin_amdgcn_readlane(__float_as_int(qx), L));
      float ncy = __int_as_float(__builtin_amdgcn_readlane(__float_as_int(qy), L));
      float ncz = __int_as_float(__builtin_amdgcn_readlane(__float_as_int(qz), L));
      if (lane == 0) {
        s_bc[i & 1][0] = ncx; s_bc[i & 1][1] = ncy; s_bc[i & 1][2] = ncz;
      }
    }
    __syncthreads();
    cx = s_bc[i & 1][0]; cy = s_bc[i & 1][1]; cz = s_bc[i & 1][2];
  }
}

// ---------------- Ball query ----------------
#define BQ_NT  256
#define BQ_CAP 2048   // expected ~209 candidates/centroid; huge safety margin

__global__ __launch_bounds__(BQ_NT) void ballq_kernel(
    const float* __restrict__ pos,
    const float* __restrict__ cent,   // centroid coords (from d_out)
    int* __restrict__ nbr,            // [M_CENT*K_LOC]
    int* __restrict__ nsel)           // [M_CENT]
{
  __shared__ float s_d2[BQ_CAP];
  __shared__ int   s_idx[BQ_CAP];
  __shared__ int   s_count;
  __shared__ u64   s_red[BQ_NT/64];
  __shared__ u64   s_win;

  const int m = blockIdx.x, tid = threadIdx.x;
  if (tid == 0) s_count = 0;
  __syncthreads();
  const float cx = cent[3*m+0], cy = cent[3*m+1], cz = cent[3*m+2];

  for (int n = tid; n < N_PTS; n += BQ_NT) {
    float dx = __fsub_rn(cx, pos[3*n+0]);
    float dy = __fsub_rn(cy, pos[3*n+1]);
    float dz = __fsub_rn(cz, pos[3*n+2]);
    float d2 = __fadd_rn(__fadd_rn(__fmul_rn(dx,dx), __fmul_rn(dy,dy)),
                         __fmul_rn(dz,dz));
    if (d2 <= 0.01f) {   // same f32 value as (float)(0.1*0.1)
      int p = atomicAdd(&s_count, 1);
      if (p < BQ_CAP) { s_d2[p] = d2; s_idx[p] = n; }
    }
  }
  __syncthreads();
  int cnt = s_count; if (cnt > BQ_CAP) cnt = BQ_CAP;
  int ns = cnt < K_LOC ? cnt : K_LOC;

  // exact top_k semantics: k smallest d2, ties -> smaller index
  for (int sel = 0; sel < ns; sel++) {
    u64 best = ~0ull;
    for (int p = tid; p < cnt; p += BQ_NT) {
      u64 pk = ((u64)__float_as_uint(s_d2[p]) << 32) | (u64)(u32)s_idx[p];
      if (pk < best) best = pk;
    }
#pragma unroll
    for (int off = 32; off >= 1; off >>= 1) {
      u64 o = __shfl_down(best, off, 64);
      if (o < best) best = o;
    }
    if ((tid & 63) == 0) s_red[tid >> 6] = best;
    __syncthreads();
    if (tid < 64) {
      best = (tid < BQ_NT/64) ? s_red[tid] : ~0ull;
#pragma unroll
      for (int off = 2; off >= 1; off >>= 1) {
        u64 o = __shfl_down(best, off, 64);
        if (o < best) best = o;
      }
      if (tid == 0) s_win = best;
    }
    __syncthreads();
    int widx = (int)(u32)(s_win & 0xFFFFFFFFull);
    if (tid == 0) nbr[m*K_LOC + sel] = widx;
    for (int p = tid; p < cnt; p += BQ_NT) {
      if (s_idx[p] == widx) s_d2[p] = FLT_MAX;   // remove winner
    }
    __syncthreads();
  }
  if (tid == 0) nsel[m] = ns;
}

// ---------------- Gather + max-pool + channel mix ----------------
// Max over the valid selected set == reference (fallback idx is the nearest
// valid neighbor, already a member of the set).
__global__ __launch_bounds__(C_CH) void pool_mix_kernel(
    const float* __restrict__ fs,   // (N,128,1)
    const float* __restrict__ fv,   // (N,128,3)
    const float* __restrict__ Ws,
    const float* __restrict__ Wv,
    const float* __restrict__ bs,
    const float* __restrict__ bv,
    const int* __restrict__ nbr,
    const int* __restrict__ nsel,
    float* __restrict__ out_s,      // (M,128,1)
    float* __restrict__ out_v)      // (M,128,3)
{
  __shared__ float ps[C_CH];
  __shared__ float pv[C_CH*3];
  const int m = blockIdx.x, o = threadIdx.x;
  const int ns = nsel[m];
  float mS = -FLT_MAX, m0 = -FLT_MAX, m1 = -FLT_MAX, m2 = -FLT_MAX;
  for (int j = 0; j < ns; j++) {
    int n = nbr[m*K_LOC + j];
    mS = fmaxf(mS, fs[(size_t)n*C_CH + o]);
    const float* r = fv + (size_t)n*(C_CH*3) + 3*o;
    m0 = fmaxf(m0, r[0]); m1 = fmaxf(m1, r[1]); m2 = fmaxf(m2, r[2]);
  }
  ps[o] = mS; pv[3*o+0] = m0; pv[3*o+1] = m1; pv[3*o+2] = m2;
  __syncthreads();
  float aS = bs[o];
  float a0 = bv[o], a1 = bv[o], a2 = bv[o];
  for (int cc = 0; cc < C_CH; cc++) {
    float w1 = Ws[cc*C_CH + o];
    float w2 = Wv[cc*C_CH + o];
    aS = fmaf(ps[cc], w1, aS);
    a0 = fmaf(pv[3*cc+0], w2, a0);
    a1 = fmaf(pv[3*cc+1], w2, a1);
    a2 = fmaf(pv[3*cc+2], w2, a2);
  }
  out_s[(size_t)m*C_CH + o] = aS;
  float* ov = out_v + (size_t)m*(C_CH*3) + 3*o;
  ov[0] = a0; ov[1] = a1; ov[2] = a2;
}

extern "C" void kernel_launch(void* const* d_in, const int* in_sizes, int n_in,
                              void* d_out, int out_size, void* d_ws, size_t ws_size,
                              hipStream_t stream) {
  (void)in_sizes; (void)n_in; (void)out_size; (void)ws_size;
  const float* pos = (const float*)d_in[0];
  const float* fs  = (const float*)d_in[1];
  const float* fv  = (const float*)d_in[2];
  const float* Ws  = (const float*)d_in[3];
  const float* Wv  = (const float*)d_in[4];
  const float* bs  = (const float*)d_in[5];
  const float* bv  = (const float*)d_in[6];

  float* out      = (float*)d_out;
  float* cent_out = out;                               // 2048*3
  float* out_s    = out + 3*M_CENT;                    // 2048*128
  float* out_v    = out + 3*M_CENT + M_CENT*C_CH;      // 2048*128*3

  char* ws = (char*)d_ws;
  u64* slots = (u64*)ws;                               // 64*14*8*8B = 57344 B
  size_t slots_bytes = (size_t)FPS_R * FPS_NB * SLOT_U64 * 8;
  int* nbr   = (int*)(ws + slots_bytes);               // 256 KB
  int* nsel  = (int*)(ws + slots_bytes + (size_t)M_CENT*K_LOC*4);

  init_ws_kernel<<<(FPS_R*FPS_NB*SLOT_U64 + 255)/256, 256, 0, stream>>>(slots);
  fps_kernel<<<FPS_NB, FPS_NT, 0, stream>>>(pos, slots, cent_out);
  ballq_kernel<<<M_CENT, BQ_NT, 0, stream>>>(pos, cent_out, nbr, nsel);
  pool_mix_kernel<<<M_CENT, C_CH, 0, stream>>>(fs, fv, Ws, Wv, bs, bv,
                                               nbr, nsel, out_s, out_v);
}